// Round 5
// baseline (459.098 us; speedup 1.0000x reference)
//
#include <hip/hip_runtime.h>

// MoE MLP: B=2,S=2048,H=1024,I=2048,E=8,TOPK=2  -> T=4096 tokens, 8192 entries.
// R11: revert to R8 pipeline (ent+combine; atomics rejected in R10). One
// change: both GEMM K-loops are now DOUBLE-BUFFERED with ONE barrier per
// K-step (T3-minimum): issue next-tile loads (A ld16 + B fp32->reg) BEFORE
// the current tile's MFMAs, ds_write next-B after them, then __syncthreads.
// Buffers are distinct static __shared__ arrays (2x-unrolled loop, macros)
// so the compiler can prove no alias between staging writes and frag reads.
// LDS 96KB -> 1 block/CU; dbuf self-hiding replaces cross-block overlap.

#define H_DIM 1024
#define I_DIM 2048
#define N_EXP 8
#define N_TOK 4096
#define N_ENT 8192
#define CAP   9216   // 8192 + 8*128 padding capacity (segments padded to 128)

typedef __attribute__((ext_vector_type(8))) short bhalf8;
typedef __attribute__((ext_vector_type(4))) float floatx4;

__device__ __forceinline__ unsigned short f2bf(float f) {
  unsigned int u = __float_as_uint(f);
  u += 0x7fffu + ((u >> 16) & 1u);   // RNE
  return (unsigned short)(u >> 16);
}

// pack two fp32 -> bf16x2 (round-half-up), one v_perm_b32
__device__ __forceinline__ unsigned int pkbf(float a, float b) {
  unsigned int ua = __float_as_uint(a) + 0x8000u;
  unsigned int ub = __float_as_uint(b) + 0x8000u;
  return __builtin_amdgcn_perm(ub, ua, 0x07060302u);  // low16=a_hi, high16=b_hi
}

__device__ __forceinline__ void ld16(const void* g, void* l) {
  __builtin_amdgcn_global_load_lds(
      (const __attribute__((address_space(1))) unsigned int*)g,
      (__attribute__((address_space(3))) unsigned int*)l, 16, 0, 0);
}

// ---------------- prep: x cast (blocks 0..2047) + routing (block 2048) ------
__global__ __launch_bounds__(256) void prep_kernel(
    const float* __restrict__ x, unsigned short* __restrict__ xb,
    const int* __restrict__ idx, const float* __restrict__ wts,
    int* __restrict__ perm, float* __restrict__ pw, int* __restrict__ inv,
    int* __restrict__ counts, int* __restrict__ poff)
{
  __shared__ int cnt[N_EXP], cur[N_EXP], off[N_EXP];
  const int t = threadIdx.x;
  if (blockIdx.x < (N_TOK * H_DIM) / (256 * 8)) {
    size_t i = ((size_t)blockIdx.x * 256 + t) * 8;
    const float4* sp = (const float4*)(x + i);
    float4 a = sp[0], b = sp[1];
    bhalf8 o;
    o[0] = (short)f2bf(a.x); o[1] = (short)f2bf(a.y); o[2] = (short)f2bf(a.z); o[3] = (short)f2bf(a.w);
    o[4] = (short)f2bf(b.x); o[5] = (short)f2bf(b.y); o[6] = (short)f2bf(b.z); o[7] = (short)f2bf(b.w);
    *(bhalf8*)(xb + i) = o;
    return;
  }
  // routing block
  if (t < N_EXP) { cnt[t] = 0; cur[t] = 0; }
  __syncthreads();
  for (int i = t; i < N_ENT; i += 256) atomicAdd(&cnt[idx[i] & 7], 1);
  __syncthreads();
  if (t == 0) {
    int o = 0;
    for (int e = 0; e < N_EXP; e++) {
      off[e] = o; counts[e] = cnt[e]; poff[e] = o;
      o += ((cnt[e] + 127) >> 7) << 7;
    }
  }
  __syncthreads();
  for (int i = t; i < N_ENT; i += 256) {
    int e = idx[i] & 7;
    int p = atomicAdd(&cur[e], 1);
    int pos = off[e] + p;
    perm[pos] = i >> 1;
    pw[pos] = wts[i];
    inv[i] = pos;
  }
}

// ---------------- GEMM1: act = silu(X Wg^T) * (X Wu^T) ----------------
// 512 threads, block tile 256(M) x 64(N) x 2 matrices, BK=64, DOUBLE-BUFFERED.
#define G1_STAGE_A(ASX, KOFF)                                               \
  _Pragma("unroll")                                                         \
  for (int t_ = 0; t_ < 4; t_++) ld16(pA[t_] + (KOFF), &ASX[lAo[t_]]);

#define G1_LOAD_B(KOFF)                                                     \
  g0 = *(const float4*)(pg + (KOFF));  g1 = *(const float4*)(pg + (KOFF) + 4); \
  u0 = *(const float4*)(pu + (KOFF));  u1 = *(const float4*)(pu + (KOFF) + 4);

#define G1_WRITE_B(BGX, BUX)                                                \
  *(uint4*)&BGX[bo] = make_uint4(pkbf(g0.x, g0.y), pkbf(g0.z, g0.w),        \
                                 pkbf(g1.x, g1.y), pkbf(g1.z, g1.w));       \
  *(uint4*)&BUX[bo] = make_uint4(pkbf(u0.x, u0.y), pkbf(u0.z, u0.w),        \
                                 pkbf(u1.x, u1.y), pkbf(u1.z, u1.w));

#define G1_COMPUTE(ASX, BGX, BUX)                                           \
  _Pragma("unroll")                                                         \
  for (int kk = 0; kk < 2; kk++) {                                          \
    const int kq = kk * 4 + quad;                                           \
    const int ko = (kq ^ s7) * 8;                                           \
    bhalf8 a_[4], bg_[2], bu_[2];                                           \
    _Pragma("unroll")                                                       \
    for (int i = 0; i < 4; i++)                                             \
      a_[i] = *(const bhalf8*)&ASX[(wmi * 64 + i * 16 + lm) * 64 + ko];     \
    _Pragma("unroll")                                                       \
    for (int j = 0; j < 2; j++) {                                           \
      bg_[j] = *(const bhalf8*)&BGX[(wnj * 32 + j * 16 + lm) * 64 + ko];    \
      bu_[j] = *(const bhalf8*)&BUX[(wnj * 32 + j * 16 + lm) * 64 + ko];    \
    }                                                                       \
    _Pragma("unroll")                                                       \
    for (int i = 0; i < 4; i++)                                             \
      _Pragma("unroll")                                                     \
      for (int j = 0; j < 2; j++) {                                         \
        accg[i][j] = __builtin_amdgcn_mfma_f32_16x16x32_bf16(a_[i], bg_[j], accg[i][j], 0, 0, 0); \
        accu[i][j] = __builtin_amdgcn_mfma_f32_16x16x32_bf16(a_[i], bu_[j], accu[i][j], 0, 0, 0); \
      }                                                                     \
  }

__global__ __launch_bounds__(512, 2) void gemm1_kernel(
    const unsigned short* __restrict__ xb,
    const float* __restrict__ gw,
    const float* __restrict__ uw,
    const int* __restrict__ perm,
    const int* __restrict__ counts,
    const int* __restrict__ poff,
    unsigned short* __restrict__ act)
{
  const int e = blockIdx.z;
  const int Ne = counts[e];
  const int mt = blockIdx.y;
  if (mt * 256 >= Ne) return;
  const int NeR = ((Ne + 127) >> 7) << 7;
  const int base = poff[e];
  const int n0 = blockIdx.x * 64;

  __shared__ __align__(16) unsigned short As0[256 * 64];   // 32 KB
  __shared__ __align__(16) unsigned short As1[256 * 64];   // 32 KB
  __shared__ __align__(16) unsigned short Bg0[64 * 64];    //  8 KB
  __shared__ __align__(16) unsigned short Bg1[64 * 64];    //  8 KB
  __shared__ __align__(16) unsigned short Bu0[64 * 64];    //  8 KB
  __shared__ __align__(16) unsigned short Bu1[64 * 64];    //  8 KB

  const int tid = threadIdx.x;
  const int lane = tid & 63;
  const int w = tid >> 6;          // 0..7
  const int wmi = w >> 1;          // 0..3 (M)
  const int wnj = w & 1;           // 0..1 (N)
  const int i3 = lane >> 3, i7 = lane & 7;
  const int swc = (i7 ^ i3) * 8;   // pre-swizzled k-chunk offset

  // A: 4 ld16/wave -> 32 rows
  const unsigned short* pA[4]; int lAo[4];
#pragma unroll
  for (int t = 0; t < 4; t++) {
    int rloc = w * 32 + t * 8 + i3;
    int rr = mt * 256 + rloc; rr = rr < Ne ? rr : Ne - 1;
    pA[t] = xb + (size_t)perm[base + rr] * H_DIM + swc;
    lAo[t] = (w * 32 + t * 8) * 64;
  }
  // B: 1 cell per thread per matrix: row nloc = w*8+i3, chunk i7 (8 fp32)
  const int nlocB = w * 8 + i3;
  const size_t wb = (size_t)e * (I_DIM * H_DIM) + (size_t)(n0 + nlocB) * H_DIM + i7 * 8;
  const float* pg = gw + wb;
  const float* pu = uw + wb;
  const int bo = nlocB * 64 + ((i7 ^ i3) * 8);   // swizzled: chunk slot i7^(row&7)

  floatx4 zero = {0.f, 0.f, 0.f, 0.f};
  floatx4 accg[4][2], accu[4][2];
#pragma unroll
  for (int i = 0; i < 4; i++)
#pragma unroll
    for (int j = 0; j < 2; j++) { accg[i][j] = zero; accu[i][j] = zero; }

  const int quad = lane >> 4, lm = lane & 15;
  const int s7 = lm & 7;

  float4 g0, g1, u0, u1;

  // prologue: stage K-tile 0 into buf0
  G1_STAGE_A(As0, 0);
  G1_LOAD_B(0);
  G1_WRITE_B(Bg0, Bu0);
  __syncthreads();

  for (int k0 = 0; k0 < H_DIM - 128; k0 += 128) {
    // sub-step A: stage tile k0+64 -> buf1, compute tile k0 from buf0
    G1_STAGE_A(As1, k0 + 64);
    G1_LOAD_B(k0 + 64);
    G1_COMPUTE(As0, Bg0, Bu0);
    G1_WRITE_B(Bg1, Bu1);
    __syncthreads();
    // sub-step B: stage tile k0+128 -> buf0, compute tile k0+64 from buf1
    G1_STAGE_A(As0, k0 + 128);
    G1_LOAD_B(k0 + 128);
    G1_COMPUTE(As1, Bg1, Bu1);
    G1_WRITE_B(Bg0, Bu0);
    __syncthreads();
  }
  // tail pair: buf0 holds tile H-128; stage H-64 -> buf1, compute both
  G1_STAGE_A(As1, H_DIM - 64);
  G1_LOAD_B(H_DIM - 64);
  G1_COMPUTE(As0, Bg0, Bu0);
  G1_WRITE_B(Bg1, Bu1);
  __syncthreads();
  G1_COMPUTE(As1, Bg1, Bu1);

#pragma unroll
  for (int i = 0; i < 4; i++) {
#pragma unroll
    for (int r = 0; r < 4; r++) {
      int row = mt * 256 + wmi * 64 + i * 16 + quad * 4 + r;
      if (row < NeR) {
        size_t rowoff = (size_t)(base + row) * I_DIM;
#pragma unroll
        for (int j = 0; j < 2; j++) {
          int col = n0 + wnj * 32 + j * 16 + lm;
          float g = accg[i][j][r];
          float u = accu[i][j][r];
          float h = (g / (1.f + __expf(-g))) * u;
          act[rowoff + col] = (unsigned short)f2bf(h);
        }
      }
    }
  }
}

// ---------------- GEMM2: ent[half][row] = pw[row]*(act x down^T over K-half) --
// 512 threads, block tile 256x128, BK=64, split-K=2, DOUBLE-BUFFERED.
#define G2_STAGE_A(ASX, KOFF)                                               \
  _Pragma("unroll")                                                         \
  for (int t_ = 0; t_ < 4; t_++) ld16(pA[t_] + (KOFF), &ASX[lAo[t_]]);

#define G2_LOAD_B(KOFF)                                                     \
  b00 = *(const float4*)(pB[0] + (KOFF)); b01 = *(const float4*)(pB[0] + (KOFF) + 4); \
  b10 = *(const float4*)(pB[1] + (KOFF)); b11 = *(const float4*)(pB[1] + (KOFF) + 4);

#define G2_WRITE_B(BSX)                                                     \
  *(uint4*)&BSX[boB[0]] = make_uint4(pkbf(b00.x, b00.y), pkbf(b00.z, b00.w),\
                                     pkbf(b01.x, b01.y), pkbf(b01.z, b01.w));\
  *(uint4*)&BSX[boB[1]] = make_uint4(pkbf(b10.x, b10.y), pkbf(b10.z, b10.w),\
                                     pkbf(b11.x, b11.y), pkbf(b11.z, b11.w));

#define G2_COMPUTE(ASX, BSX)                                                \
  _Pragma("unroll")                                                         \
  for (int kk = 0; kk < 2; kk++) {                                          \
    const int kq = kk * 4 + quad;                                           \
    const int ko = (kq ^ s7) * 8;                                           \
    bhalf8 a_[4], b_[4];                                                    \
    _Pragma("unroll")                                                       \
    for (int i = 0; i < 4; i++)                                             \
      a_[i] = *(const bhalf8*)&ASX[(wmi * 64 + i * 16 + lm) * 64 + ko];     \
    _Pragma("unroll")                                                       \
    for (int j = 0; j < 4; j++)                                             \
      b_[j] = *(const bhalf8*)&BSX[(wnj * 64 + j * 16 + lm) * 64 + ko];     \
    _Pragma("unroll")                                                       \
    for (int i = 0; i < 4; i++)                                             \
      _Pragma("unroll")                                                     \
      for (int j = 0; j < 4; j++)                                           \
        acc[i][j] = __builtin_amdgcn_mfma_f32_16x16x32_bf16(a_[i], b_[j], acc[i][j], 0, 0, 0); \
  }

__global__ __launch_bounds__(512, 2) void gemm2_kernel(
    const unsigned short* __restrict__ act,
    const float* __restrict__ dw,
    const float* __restrict__ pw,
    const int* __restrict__ counts,
    const int* __restrict__ poff,
    float* __restrict__ ent)
{
  const int e = blockIdx.z;
  const int Ne = counts[e];
  const int mt = blockIdx.y;
  if (mt * 256 >= Ne) return;
  const int NeR = ((Ne + 127) >> 7) << 7;
  const int base = poff[e];
  const int n0 = (blockIdx.x & 7) * 128;
  const int k_lo = (blockIdx.x >> 3) * (I_DIM / 2);
  const int KLEN = I_DIM / 2;

  __shared__ __align__(16) unsigned short As0[256 * 64];   // 32 KB
  __shared__ __align__(16) unsigned short As1[256 * 64];   // 32 KB
  __shared__ __align__(16) unsigned short Bs0[128 * 64];   // 16 KB
  __shared__ __align__(16) unsigned short Bs1[128 * 64];   // 16 KB

  const int tid = threadIdx.x;
  const int lane = tid & 63;
  const int w = tid >> 6;
  const int wmi = w >> 1, wnj = w & 1;
  const int i3 = lane >> 3, i7 = lane & 7;
  const int swc = (i7 ^ i3) * 8;

  const unsigned short* pA[4]; int lAo[4];
#pragma unroll
  for (int t = 0; t < 4; t++) {
    int rloc = w * 32 + t * 8 + i3;
    int rr = mt * 256 + rloc; rr = rr < NeR ? rr : NeR - 1;
    pA[t] = act + (size_t)(base + rr) * I_DIM + k_lo + swc;
    lAo[t] = (w * 32 + t * 8) * 64;
  }
  // B: 2 cells/thread: rows w*16+{0,8}+i3, chunk i7
  const float* pB[2]; int boB[2];
#pragma unroll
  for (int t = 0; t < 2; t++) {
    int rloc = w * 16 + t * 8 + i3;
    pB[t] = dw + (size_t)e * (H_DIM * I_DIM) + (size_t)(n0 + rloc) * I_DIM + k_lo + i7 * 8;
    boB[t] = rloc * 64 + ((i7 ^ i3) * 8);   // rloc&7 == i3
  }

  floatx4 zero = {0.f, 0.f, 0.f, 0.f};
  floatx4 acc[4][4];
#pragma unroll
  for (int i = 0; i < 4; i++)
#pragma unroll
    for (int j = 0; j < 4; j++) acc[i][j] = zero;

  const int quad = lane >> 4, lm = lane & 15;
  const int s7 = lm & 7;

  float4 b00, b01, b10, b11;

  // prologue: stage K-tile 0 into buf0
  G2_STAGE_A(As0, 0);
  G2_LOAD_B(0);
  G2_WRITE_B(Bs0);
  __syncthreads();

  for (int k0 = 0; k0 < KLEN - 128; k0 += 128) {
    G2_STAGE_A(As1, k0 + 64);
    G2_LOAD_B(k0 + 64);
    G2_COMPUTE(As0, Bs0);
    G2_WRITE_B(Bs1);
    __syncthreads();
    G2_STAGE_A(As0, k0 + 128);
    G2_LOAD_B(k0 + 128);
    G2_COMPUTE(As1, Bs1);
    G2_WRITE_B(Bs0);
    __syncthreads();
  }
  G2_STAGE_A(As1, KLEN - 64);
  G2_LOAD_B(KLEN - 64);
  G2_COMPUTE(As0, Bs0);
  G2_WRITE_B(Bs1);
  __syncthreads();
  G2_COMPUTE(As1, Bs1);

  float* enth = ent + (size_t)(blockIdx.x >> 3) * CAP * H_DIM;
#pragma unroll
  for (int i = 0; i < 4; i++) {
#pragma unroll
    for (int r = 0; r < 4; r++) {
      int row = mt * 256 + wmi * 64 + i * 16 + quad * 4 + r;
      if (row < Ne) {
        float wt = pw[base + row];
        float* orow = enth + (size_t)(base + row) * H_DIM;
#pragma unroll
        for (int j = 0; j < 4; j++) {
          int col = n0 + wnj * 64 + j * 16 + lm;
          orow[col] = wt * acc[i][j][r];
        }
      }
    }
  }
}

// ---------------- combine ----------------
__global__ __launch_bounds__(256) void combine_kernel(
    const float* __restrict__ ent, const int* __restrict__ inv,
    float* __restrict__ out)
{
  const int t = blockIdx.x;
  const int p0 = inv[2 * t], p1 = inv[2 * t + 1];
  const float4* r0 = (const float4*)(ent + (size_t)p0 * H_DIM);
  const float4* r1 = (const float4*)(ent + (size_t)p1 * H_DIM);
  const float4* r2 = (const float4*)(ent + (size_t)(CAP + p0) * H_DIM);
  const float4* r3 = (const float4*)(ent + (size_t)(CAP + p1) * H_DIM);
  float4 a = r0[threadIdx.x], b = r1[threadIdx.x];
  float4 c = r2[threadIdx.x], d = r3[threadIdx.x];
  float4 o = {a.x + b.x + c.x + d.x, a.y + b.y + c.y + d.y,
              a.z + b.z + c.z + d.z, a.w + b.w + c.w + d.w};
  ((float4*)(out + (size_t)t * H_DIM))[threadIdx.x] = o;
}

extern "C" void kernel_launch(void* const* d_in, const int* in_sizes, int n_in,
                              void* d_out, int out_size, void* d_ws, size_t ws_size,
                              hipStream_t stream) {
  const float* x    = (const float*)d_in[0];
  const int*   idx  = (const int*)d_in[1];
  const float* wts  = (const float*)d_in[2];
  const float* gate = (const float*)d_in[3];
  const float* up   = (const float*)d_in[4];
  const float* down = (const float*)d_in[5];
  float* out = (float*)d_out;
  char* ws = (char*)d_ws;

  // workspace layout (bytes)
  float*          ent = (float*)(ws + 0);                   // 75,497,472 (2*CAP*H*4)
  unsigned short* act = (unsigned short*)(ws + 75497472);   // 37,748,736 (CAP*I*2)
  unsigned short* xb  = (unsigned short*)(ws + 113246208);  //  8,388,608
  int*   perm   = (int*)(ws + 121634816);                   // 36,864
  float* pw     = (float*)(ws + 121671680);                 // 36,864
  int*   inv    = (int*)(ws + 121708544);                   // 32,768
  int*   counts = (int*)(ws + 121741312);                   // 32
  int*   poff   = (int*)(ws + 121741376);                   // 32

  prep_kernel<<<(N_TOK * H_DIM) / (256 * 8) + 1, 256, 0, stream>>>(
      x, xb, idx, wts, perm, pw, inv, counts, poff);

  gemm1_kernel<<<dim3(I_DIM / 64, 32, N_EXP), 512, 0, stream>>>(
      xb, gate, up, perm, counts, poff, act);

  gemm2_kernel<<<dim3(16, 32, N_EXP), 512, 0, stream>>>(
      act, down, pw, counts, poff, ent);

  combine_kernel<<<N_TOK, 256, 0, stream>>>(ent, inv, out);
}